// Round 12
// baseline (1517.069 us; speedup 1.0000x reference)
//
#include <hip/hip_runtime.h>
#include <hip/hip_fp16.h>

#define CIN 32
#define COUT 32
#define LRELU_SLOPE 0.01f
#define BN_EPS 1e-5f
#define CHUNK 2048
#define KMAX 27
#define NBUCK 256
#define BCH 4096

typedef _Float16 half2_t __attribute__((ext_vector_type(2)));

#if __has_builtin(__builtin_amdgcn_fdot2)
#define FDOT2(a, b, c) __builtin_amdgcn_fdot2((a), (b), (c), false)
#else
static __device__ __forceinline__ float fdot2_sw(half2_t a, half2_t b, float c) {
    return (float)a.x * (float)b.x + (float)a.y * (float)b.y + c;
}
#define FDOT2(a, b, c) fdot2_sw((a), (b), (c))
#endif

#if __has_builtin(__builtin_amdgcn_cvt_pkrtz)
#define CVTPK(x, y) __builtin_bit_cast(half2_t, __builtin_amdgcn_cvt_pkrtz((x), (y)))
#else
static __device__ __forceinline__ half2_t cvtpk_sw(float x, float y) {
    half2_t r; r.x = (_Float16)x; r.y = (_Float16)y; return r;
}
#define CVTPK(x, y) cvtpk_sw((x), (y))
#endif

union HU { uint4 u; half2_t h[4]; };
union FU { uint4 u; float f[4]; };

// ---------------- CSR build ----------------

__global__ void __launch_bounds__(256) hist_kernel(
    const int* __restrict__ po, int* __restrict__ cnt, int E)
{
    int i0 = (blockIdx.x * blockDim.x + threadIdx.x) * 4;
    if (i0 + 3 < E) {
        int4 v = *(const int4*)(po + i0);
        atomicAdd(&cnt[v.x], 1);
        atomicAdd(&cnt[v.y], 1);
        atomicAdd(&cnt[v.z], 1);
        atomicAdd(&cnt[v.w], 1);
    } else {
        for (int i = i0; i < E; ++i) atomicAdd(&cnt[po[i]], 1);
    }
}

__global__ void __launch_bounds__(256) blocksum_kernel(
    const int* __restrict__ cnt, int* __restrict__ bsum, int N)
{
    int base = blockIdx.x * CHUNK + threadIdx.x * 8;
    int s = 0;
#pragma unroll
    for (int j = 0; j < 8; ++j) { int i = base + j; if (i < N) s += cnt[i]; }
#pragma unroll
    for (int off = 1; off < 64; off <<= 1) s += __shfl_xor(s, off);
    __shared__ int wsum[4];
    if ((threadIdx.x & 63) == 0) wsum[threadIdx.x >> 6] = s;
    __syncthreads();
    if (threadIdx.x == 0) bsum[blockIdx.x] = wsum[0] + wsum[1] + wsum[2] + wsum[3];
}

// parallel exclusive scan of up to 1024 block sums, one block of 256 threads
__global__ void __launch_bounds__(256) scanblk_kernel(
    const int* __restrict__ bsum, int* __restrict__ boffs, int nb)
{
    __shared__ int ts[256];
    int tid = threadIdx.x;
    int v[4]; int s = 0;
#pragma unroll
    for (int j = 0; j < 4; ++j) {
        int i = tid * 4 + j;
        v[j] = (i < nb) ? bsum[i] : 0;
        s += v[j];
    }
    ts[tid] = s;
    __syncthreads();
    for (int off = 1; off < 256; off <<= 1) {
        int add = (tid >= off) ? ts[tid - off] : 0;
        __syncthreads();
        ts[tid] += add;
        __syncthreads();
    }
    int run = ts[tid] - s;
#pragma unroll
    for (int j = 0; j < 4; ++j) {
        int i = tid * 4 + j;
        if (i < nb) { boffs[i] = run; run += v[j]; }
    }
}

__global__ void __launch_bounds__(256) scatteroffs_kernel(
    int* __restrict__ cnt, int* __restrict__ cursors,
    const int* __restrict__ boffs, int N)
{
    int tid = threadIdx.x;
    int lane = tid & 63;
    int wv = tid >> 6;
    int base = blockIdx.x * CHUNK + tid * 8;
    int c[8]; int tsum = 0;
#pragma unroll
    for (int j = 0; j < 8; ++j) { int i = base + j; c[j] = (i < N) ? cnt[i] : 0; tsum += c[j]; }
    // wave inclusive scan of tsum
    int x = tsum;
#pragma unroll
    for (int off = 1; off < 64; off <<= 1) {
        int y = __shfl_up(x, off);
        if (lane >= off) x += y;
    }
    __shared__ int wtot[4];
    if (lane == 63) wtot[wv] = x;
    __syncthreads();
    int woff = boffs[blockIdx.x];
    for (int w = 0; w < wv; ++w) woff += wtot[w];
    int off = woff + x - tsum;
#pragma unroll
    for (int j = 0; j < 8; ++j) {
        int i = base + j;
        if (i < N) { cnt[i] = off; cursors[i] = off; off += c[j]; }
    }
}

// ---------------- two-phase scatter (kills 16x write amplification) ----------------
// R11 PMC: old one-phase scatter WRITE_SIZE=425MB for a 27MB output (64B/4B
// line amplification: a row's 27 contributions arrive spread over the whole
// kernel -> its line evicted between 4B writes). Phase A bins entries into 256
// coarse buckets (po>>shift, bucket base = offsets[b<<shift], same slot-space)
// with LDS staging so global writes are sequential runs. Phase B streams each
// bucket's contiguous region and scatters within its ~110KB L2-resident CSR
// window -> lines absorb all ~16 writes before write-back.

__global__ void __launch_bounds__(256) bucketinit_kernel(
    const int* __restrict__ offsets, int* __restrict__ bucketCur,
    int N, int E, int shift)
{
    int b = threadIdx.x;
    long idx = (long)b << shift;
    bucketCur[b] = (idx < N) ? offsets[idx] : E;
}

__global__ void __launch_bounds__(256) bin_kernel(
    const int* __restrict__ pairs_out, const int* __restrict__ pairs_in,
    int* __restrict__ bucketCur, uint2* __restrict__ binned,
    int P, int shift)
{
    __shared__ uint2 buf[BCH];          // 32 KB
    __shared__ int hist[NBUCK];
    __shared__ int ts[NBUCK];
    __shared__ int lbase[NBUCK];
    __shared__ int gbase[NBUCK];
    __shared__ int lcur[NBUCK];
    int tid = threadIdx.x;
    int k = blockIdx.y;
    int p0 = blockIdx.x * BCH;
    const int* po = pairs_out + (size_t)k * P;
    const int* pi = pairs_in  + (size_t)k * P;

    hist[tid] = 0;
    __syncthreads();

    int myP[16], myV[16];
#pragma unroll
    for (int j = 0; j < 4; ++j) {
        int idx = p0 + j * 1024 + tid * 4;
        if (idx + 3 < P) {
            int4 o4 = *(const int4*)(po + idx);
            int4 i4 = *(const int4*)(pi + idx);
            myP[j*4+0] = o4.x; myV[j*4+0] = (i4.x << 6) | k;
            myP[j*4+1] = o4.y; myV[j*4+1] = (i4.y << 6) | k;
            myP[j*4+2] = o4.z; myV[j*4+2] = (i4.z << 6) | k;
            myP[j*4+3] = o4.w; myV[j*4+3] = (i4.w << 6) | k;
        } else {
#pragma unroll
            for (int q = 0; q < 4; ++q) {
                int ii = idx + q;
                if (ii < P) { myP[j*4+q] = po[ii]; myV[j*4+q] = (pi[ii] << 6) | k; }
                else myP[j*4+q] = -1;
            }
        }
    }
#pragma unroll
    for (int x = 0; x < 16; ++x)
        if (myP[x] >= 0) atomicAdd(&hist[myP[x] >> shift], 1);
    __syncthreads();

    int h = hist[tid];
    ts[tid] = h;
    __syncthreads();
    for (int off = 1; off < NBUCK; off <<= 1) {
        int add = (tid >= off) ? ts[tid - off] : 0;
        __syncthreads();
        ts[tid] += add;
        __syncthreads();
    }
    lbase[tid] = ts[tid] - h;
    lcur[tid]  = ts[tid] - h;
    if (h > 0) gbase[tid] = atomicAdd(&bucketCur[tid], h);
    __syncthreads();

#pragma unroll
    for (int x = 0; x < 16; ++x) {
        if (myP[x] >= 0) {
            int b = myP[x] >> shift;
            int pos = atomicAdd(&lcur[b], 1);
            buf[pos] = make_uint2((unsigned)myP[x], (unsigned)myV[x]);
        }
    }
    __syncthreads();
    {
        int n = hist[tid];
        if (n > 0) {
            int src = lbase[tid], dst = gbase[tid];
            for (int i = 0; i < n; ++i) binned[dst + i] = buf[src + i];
        }
    }
}

__global__ void __launch_bounds__(256) resolve_kernel(
    const uint2* __restrict__ binned, int* __restrict__ cursors,
    int* __restrict__ sorted, int E)
{
    int i0 = (blockIdx.x * 256 + threadIdx.x) * 4;
    if (i0 + 3 < E) {
        uint4 a = *(const uint4*)(binned + i0);
        uint4 b = *(const uint4*)(binned + i0 + 2);
        int s0 = atomicAdd(&cursors[a.x], 1); sorted[s0] = (int)a.y;
        int s1 = atomicAdd(&cursors[a.z], 1); sorted[s1] = (int)a.w;
        int s2 = atomicAdd(&cursors[b.x], 1); sorted[s2] = (int)b.y;
        int s3 = atomicAdd(&cursors[b.z], 1); sorted[s3] = (int)b.w;
    } else {
        for (int i = i0; i < E; ++i) {
            uint2 e = binned[i];
            int s = atomicAdd(&cursors[e.x], 1);
            sorted[s] = (int)e.y;
        }
    }
}

// fallback one-phase scatter (ws too small for binned[])
__global__ void __launch_bounds__(256) scatter_kernel(
    const int* __restrict__ pairs_out, const int* __restrict__ pairs_in,
    int* __restrict__ cursors, int* __restrict__ sorted, int P)
{
    int p0 = (blockIdx.x * blockDim.x + threadIdx.x) * 4;
    int k = blockIdx.y;
    const int* po = pairs_out + (size_t)k * P;
    const int* pi = pairs_in + (size_t)k * P;
    if (p0 + 3 < P) {
        int4 o4 = *(const int4*)(po + p0);
        int4 i4 = *(const int4*)(pi + p0);
        int s0 = atomicAdd(&cursors[o4.x], 1); sorted[s0] = (i4.x << 6) | k;
        int s1 = atomicAdd(&cursors[o4.y], 1); sorted[s1] = (i4.y << 6) | k;
        int s2 = atomicAdd(&cursors[o4.z], 1); sorted[s2] = (i4.z << 6) | k;
        int s3 = atomicAdd(&cursors[o4.w], 1); sorted[s3] = (i4.w << 6) | k;
    } else {
        for (int p = p0; p < P; ++p) {
            int slot = atomicAdd(&cursors[po[p]], 1);
            sorted[slot] = (pi[p] << 6) | k;
        }
    }
}

// ---------------- features -> f16 pre-convert ----------------

__global__ void __launch_bounds__(256) cvt_kernel(
    const float* __restrict__ f, __half* __restrict__ o, int n8)
{
    int i = blockIdx.x * 256 + threadIdx.x;
    if (i >= n8) return;
    const float4* s = (const float4*)f + (size_t)i * 2;
    float4 a = s[0], b = s[1];
    union { uint4 u; __half h[8]; } r;
    r.h[0] = __float2half(a.x); r.h[1] = __float2half(a.y);
    r.h[2] = __float2half(a.z); r.h[3] = __float2half(a.w);
    r.h[4] = __float2half(b.x); r.h[5] = __float2half(b.y);
    r.h[6] = __float2half(b.z); r.h[7] = __float2half(b.w);
    ((uint4*)o)[i] = r.u;
}

// ---------------- fused conv + lrelu + stats ----------------
// 512-thread blocks (8 waves share one 28KB W-copy): 4 blocks/CU = 32 waves/CU.
// Two half-N dispatches (observability). co-half from blockIdx bit 3 (same-XCD
// sibling: halved FETCH, R8). Entry word via readlane -> SALU decode. W_k LDS
// slice 1KB contiguous, conflict-free. Stats dup j-lanes: last-writer-wins.

template<int PC>
__global__ void __launch_bounds__(512, 8) fused_wave_kernel(
    const float* __restrict__ features,
    const __half* __restrict__ feat16,
    const float* __restrict__ weight,
    const int* __restrict__ sorted,
    const int* __restrict__ offsets,
    float* __restrict__ out,
    float* __restrict__ gstats,         // [0..31] sum, [32..63] sumsq
    int N, int E, int rowBase, int rowCount, int rpw, int KW)
{
    __shared__ __align__(16) __half wlds[KMAX * 512];   // [k][co_local(16)][c(32)] = 27,648 B
    __shared__ float sred[8][16];
    __shared__ float qred[8][16];

    const int co_base = ((blockIdx.x >> 3) & 1) << 4;
    const int rg = (blockIdx.x & 7) | ((blockIdx.x >> 4) << 3);

    // stage W slice: global fp32 [k][c][co] -> LDS f16 [k][co_local][c]
    for (int s = threadIdx.x; s < KW * 512; s += 512) {
        int co_l = s & 15, c = (s >> 4) & 31, k = s >> 9;
        wlds[k * 512 + co_l * 32 + c] =
            __float2half(weight[k * 1024 + c * 32 + co_base + co_l]);
    }
    __syncthreads();

    const int lane = threadIdx.x & 63;
    const int wv = threadIdx.x >> 6;   // 0..7
    const int j = lane & 3;            // c-quarter
    const int co_l = lane >> 2;        // 0..15
    const int gw = rg * 8 + wv;
    const int wlane_off = lane << 4;
    const char* wbase = (const char*)wlds;
    const char* fbase = PC ? (const char*)feat16 : (const char*)features;

    float ssum = 0.f, qsum = 0.f;

    int i0 = rowBase + gw * rpw;
    int i1 = i0 + rpw;
    int rend = rowBase + rowCount; if (rend > N) rend = N;
    if (i1 > rend) i1 = rend;

#define LOADE(F0, F1, W0, IDX) do {                                               \
    int _ii = (IDX); _ii = _ii < 63 ? _ii : 63;                                   \
    int _pk = __builtin_amdgcn_readlane(pkl, _ii);                                \
    W0 = *(const uint4*)(wbase + ((_pk & 63) << 10) + wlane_off);                 \
    if (PC) {                                                                     \
        const char* _sb = fbase + (unsigned)(_pk & 0xFFFFFFC0);                   \
        F0 = *(const uint4*)(_sb + (j << 4));                                     \
    } else {                                                                      \
        const char* _sb = fbase + ((size_t)(unsigned)(_pk & 0xFFFFFFC0) << 1);    \
        F0 = *(const uint4*)(_sb + (j << 5));                                     \
        F1 = *(const uint4*)(_sb + (j << 5) + 16);                                \
    }                                                                             \
} while (0)

#define DOTS(F0, F1, W0) do {                                                     \
    HU _w; _w.u = W0;                                                             \
    half2_t _p0, _p1, _p2, _p3;                                                   \
    if (PC) {                                                                     \
        HU _f; _f.u = F0;                                                         \
        _p0 = _f.h[0]; _p1 = _f.h[1]; _p2 = _f.h[2]; _p3 = _f.h[3];               \
    } else {                                                                      \
        FU _a, _b; _a.u = F0; _b.u = F1;                                          \
        _p0 = CVTPK(_a.f[0], _a.f[1]); _p1 = CVTPK(_a.f[2], _a.f[3]);             \
        _p2 = CVTPK(_b.f[0], _b.f[1]); _p3 = CVTPK(_b.f[2], _b.f[3]);             \
    }                                                                             \
    acc0 = FDOT2(_p0, _w.h[0], acc0); acc1 = FDOT2(_p1, _w.h[1], acc1);           \
    acc0 = FDOT2(_p2, _w.h[2], acc0); acc1 = FDOT2(_p3, _w.h[3], acc1);           \
} while (0)

#define WINDOW() do {                                                             \
    uint4 fA0, fA1, wA0, fB0, fB1, wB0, fC0, fC1, wC0, fD0, fD1, wD0;             \
    LOADE(fA0, fA1, wA0, 0);                                                      \
    LOADE(fB0, fB1, wB0, 1);                                                      \
    LOADE(fC0, fC1, wC0, 2);                                                      \
    LOADE(fD0, fD1, wD0, 3);                                                      \
    for (int e = 0; e < m; e += 4) {                                              \
        DOTS(fA0, fA1, wA0); LOADE(fA0, fA1, wA0, e + 4);                         \
        if (e + 1 < m) { DOTS(fB0, fB1, wB0); LOADE(fB0, fB1, wB0, e + 5); }      \
        if (e + 2 < m) { DOTS(fC0, fC1, wC0); LOADE(fC0, fC1, wC0, e + 6); }      \
        if (e + 3 < m) { DOTS(fD0, fD1, wD0); LOADE(fD0, fD1, wD0, e + 7); }      \
    }                                                                             \
} while (0)

    if (i0 < rend) {
        int beg = offsets[i0];
        int pklA;
        {
            int end0 = (i0 == N - 1) ? E : offsets[i0 + 1];
            int m0 = end0 - beg; if (m0 > 64) m0 = 64;
            pklA = (lane < m0) ? sorted[beg + lane] : 0;
        }
        for (int r = i0; r < i1; ++r) {
            int end = (r == N - 1) ? E : offsets[r + 1];
            int pklB = 0;
            if (r + 1 < i1) {
                int endn = (r + 1 == N - 1) ? E : offsets[r + 2];
                int mn = endn - end; if (mn > 64) mn = 64;
                pklB = (lane < mn) ? sorted[end + lane] : 0;
            }
            float acc0 = 0.f, acc1 = 0.f;
            if (end > beg) {
                {
                    int m = end - beg; if (m > 64) m = 64;
                    int pkl = pklA;
                    WINDOW();
                }
                for (int base = beg + 64; base < end; base += 64) {   // rare
                    int m = end - base; if (m > 64) m = 64;
                    int pkl = (lane < m) ? sorted[base + lane] : 0;
                    WINDOW();
                }
            }
            float acc = acc0 + acc1;
            acc += __shfl_xor(acc, 1);     // combine c-quarters
            acc += __shfl_xor(acc, 2);
            float act = acc >= 0.f ? acc : LRELU_SLOPE * acc;
            if (j == 0) out[(size_t)r * COUT + co_base + co_l] = act;
            ssum += act; qsum += act * act;
            beg = end; pklA = pklB;
        }
    }

#undef WINDOW
#undef LOADE
#undef DOTS

    sred[wv][co_l] = ssum;   // 4 j-lanes write identical value; one survives (correct)
    qred[wv][co_l] = qsum;
    __syncthreads();
    if (threadIdx.x < 16) {
        int t = threadIdx.x;
        float S = 0.f, Q = 0.f;
#pragma unroll
        for (int w = 0; w < 8; ++w) { S += sred[w][t]; Q += qred[w][t]; }
        atomicAdd(&gstats[co_base + t], S);
        atomicAdd(&gstats[32 + co_base + t], Q);
    }
}

// norm WITHOUT re-applying lrelu
__global__ void __launch_bounds__(256) norm2_kernel(
    float* __restrict__ data, const float* __restrict__ stats,
    const float* __restrict__ gamma, const float* __restrict__ beta,
    int n4, float invN)
{
    int i = blockIdx.x * blockDim.x + threadIdx.x;
    if (i >= n4) return;
    int qd = i & 7;
    float sc[4], bs[4];
#pragma unroll
    for (int j = 0; j < 4; ++j) {
        int c = qd * 4 + j;
        float m = stats[c] * invN;
        float v = stats[32 + c] * invN - m * m;
        float inv = rsqrtf(v + BN_EPS);
        sc[j] = inv * gamma[c];
        bs[j] = beta[c] - m * sc[j];
    }
    float4* d4 = (float4*)data;
    float4 a = d4[i];
    float4 y;
    y.x = a.x * sc[0] + bs[0];
    y.y = a.y * sc[1] + bs[1];
    y.z = a.z * sc[2] + bs[2];
    y.w = a.w * sc[3] + bs[3];
    d4[i] = y;
}

// ---------------- fallback path (atomic version) ----------------

__global__ void __launch_bounds__(256) conv_atomic_kernel(
    const float* __restrict__ features,
    const float* __restrict__ weight,
    const int* __restrict__ pairs_in,
    const int* __restrict__ pairs_out,
    float* __restrict__ out,
    int P)
{
    int p = blockIdx.x * blockDim.x + threadIdx.x;
    int k = blockIdx.y;
    if (p >= P) return;
    int pi = pairs_in[(size_t)k * P + p];
    int po = pairs_out[(size_t)k * P + p];
    const float4* __restrict__ frow = (const float4*)(features + (size_t)pi * CIN);
    const float* __restrict__ wk = weight + (size_t)k * CIN * COUT;
    float acc[COUT];
#pragma unroll
    for (int co = 0; co < COUT; ++co) acc[co] = 0.f;
#pragma unroll
    for (int c4 = 0; c4 < CIN / 4; ++c4) {
        float4 f = frow[c4];
        float fv[4] = {f.x, f.y, f.z, f.w};
#pragma unroll
        for (int j = 0; j < 4; ++j) {
            const float* __restrict__ wr = wk + (c4 * 4 + j) * COUT;
#pragma unroll
            for (int co = 0; co < COUT; ++co)
                acc[co] = fmaf(fv[j], wr[co], acc[co]);
        }
    }
    float* orow = out + (size_t)po * COUT;
#pragma unroll
    for (int co = 0; co < COUT; ++co)
        atomicAdd(orow + co, acc[co]);
}

__device__ __forceinline__ float4 lrelu4(float4 v) {
    float4 a;
    a.x = v.x >= 0.f ? v.x : LRELU_SLOPE * v.x;
    a.y = v.y >= 0.f ? v.y : LRELU_SLOPE * v.y;
    a.z = v.z >= 0.f ? v.z : LRELU_SLOPE * v.z;
    a.w = v.w >= 0.f ? v.w : LRELU_SLOPE * v.w;
    return a;
}

__global__ void __launch_bounds__(256) stats_fb_kernel(
    const float* __restrict__ conv, float* __restrict__ stats, int n4)
{
    const float4* __restrict__ c4p = (const float4*)conv;
    int stride = blockDim.x * gridDim.x;
    float4 s = {0.f, 0.f, 0.f, 0.f};
    float4 q = {0.f, 0.f, 0.f, 0.f};
    for (int i = blockIdx.x * blockDim.x + threadIdx.x; i < n4; i += stride) {
        float4 a = lrelu4(c4p[i]);
        s.x += a.x; s.y += a.y; s.z += a.z; s.w += a.w;
        q.x += a.x * a.x; q.y += a.y * a.y; q.z += a.z * a.z; q.w += a.w * a.w;
    }
#pragma unroll
    for (int off = 8; off < 64; off <<= 1) {
        s.x += __shfl_xor(s.x, off); s.y += __shfl_xor(s.y, off);
        s.z += __shfl_xor(s.z, off); s.w += __shfl_xor(s.w, off);
        q.x += __shfl_xor(q.x, off); q.y += __shfl_xor(q.y, off);
        q.z += __shfl_xor(q.z, off); q.w += __shfl_xor(q.w, off);
    }
    __shared__ float4 rs[4][8];
    __shared__ float4 rq[4][8];
    int lane = threadIdx.x & 63;
    int w = threadIdx.x >> 6;
    if (lane < 8) { rs[w][lane] = s; rq[w][lane] = q; }
    __syncthreads();
    if (threadIdx.x < 8) {
        int qd = threadIdx.x;
        float4 S = {0.f, 0.f, 0.f, 0.f};
        float4 Q = {0.f, 0.f, 0.f, 0.f};
        for (int ww = 0; ww < 4; ++ww) {
            float4 a = rs[ww][qd], b = rq[ww][qd];
            S.x += a.x; S.y += a.y; S.z += a.z; S.w += a.w;
            Q.x += b.x; Q.y += b.y; Q.z += b.z; Q.w += b.w;
        }
        atomicAdd(&stats[qd * 4 + 0], S.x); atomicAdd(&stats[qd * 4 + 1], S.y);
        atomicAdd(&stats[qd * 4 + 2], S.z); atomicAdd(&stats[qd * 4 + 3], S.w);
        atomicAdd(&stats[32 + qd * 4 + 0], Q.x); atomicAdd(&stats[32 + qd * 4 + 1], Q.y);
        atomicAdd(&stats[32 + qd * 4 + 2], Q.z); atomicAdd(&stats[32 + qd * 4 + 3], Q.w);
    }
}

__global__ void __launch_bounds__(256) norm_fb_kernel(
    float* __restrict__ data, const float* __restrict__ stats,
    const float* __restrict__ gamma, const float* __restrict__ beta,
    int n4, float invN)
{
    int i = blockIdx.x * blockDim.x + threadIdx.x;
    if (i >= n4) return;
    int qd = i & 7;
    float sc[4], bs[4];
#pragma unroll
    for (int j = 0; j < 4; ++j) {
        int c = qd * 4 + j;
        float m = stats[c] * invN;
        float v = stats[32 + c] * invN - m * m;
        float inv = rsqrtf(v + BN_EPS);
        sc[j] = inv * gamma[c];
        bs[j] = beta[c] - m * sc[j];
    }
    float4* d4 = (float4*)data;
    float4 a = lrelu4(d4[i]);
    float4 y;
    y.x = a.x * sc[0] + bs[0];
    y.y = a.y * sc[1] + bs[1];
    y.z = a.z * sc[2] + bs[2];
    y.w = a.w * sc[3] + bs[3];
    d4[i] = y;
}

extern "C" void kernel_launch(void* const* d_in, const int* in_sizes, int n_in,
                              void* d_out, int out_size, void* d_ws, size_t ws_size,
                              hipStream_t stream) {
    const float* features = (const float*)d_in[0];
    const float* weight   = (const float*)d_in[1];
    const float* gamma    = (const float*)d_in[2];
    const float* beta     = (const float*)d_in[3];
    const int* pairs_in   = (const int*)d_in[4];
    const int* pairs_out  = (const int*)d_in[5];
    float* out = (float*)d_out;

    int N  = in_sizes[0] / CIN;           // 500000
    int KW = in_sizes[1] / (CIN * COUT);  // 27
    int P  = in_sizes[4] / KW;            // 250000
    int E  = KW * P;                      // 6,750,000
    int n4 = N * (COUT / 4);

    // ws layout: stats(256B) | offsets[N] | cursors[N] | bsum[1024] | boffs[1024]
    //            | sorted[E] | pad | feat16[N*32] | pad | bucketCur[256] | binned[E]x8B
    char* wsb = (char*)d_ws;
    float* stats  = (float*)wsb;
    int* offsets  = (int*)(wsb + 256);
    int* cursors  = offsets + N;
    int* bsum     = cursors + N;
    int* boffs    = bsum + 1024;
    int* sorted   = boffs + 1024;
    __half* feat16 = (__half*)(((uintptr_t)(sorted + E) + 15) & ~(uintptr_t)15);
    int* bucketCur = (int*)(((uintptr_t)(feat16 + (size_t)N * CIN) + 15) & ~(uintptr_t)15);
    uint2* binned  = (uint2*)(bucketCur + NBUCK);   // 1024B after bucketCur, 16B-aligned

    size_t need1 = 256 + ((size_t)2 * N + 2048 + E) * 4;
    size_t need2 = need1 + 16 + (size_t)N * CIN * 2;
    size_t need3 = need2 + 16 + NBUCK * 4 + (size_t)E * 8;

    bool fast = (ws_size >= need1) && (KW <= KMAX) && (N <= (1 << 24));
    bool preconv = fast && (ws_size >= need2);
    bool twophase = preconv && (ws_size >= need3);

    if (fast) {
        hipMemsetAsync(stats, 0, 256, stream);
        hipMemsetAsync(offsets, 0, (size_t)N * sizeof(int), stream);

        hist_kernel<<<(E / 4 + 255) / 256, 256, 0, stream>>>(pairs_out, offsets, E);

        int nb = (N + CHUNK - 1) / CHUNK;
        blocksum_kernel<<<nb, 256, 0, stream>>>(offsets, bsum, N);
        scanblk_kernel<<<1, 256, 0, stream>>>(bsum, boffs, nb);
        scatteroffs_kernel<<<nb, 256, 0, stream>>>(offsets, cursors, boffs, N);

        if (twophase) {
            int shift = 0;
            while (((N - 1) >> shift) >= NBUCK) shift++;
            bucketinit_kernel<<<1, NBUCK, 0, stream>>>(offsets, bucketCur, N, E, shift);
            dim3 bgrid((P + BCH - 1) / BCH, KW);
            bin_kernel<<<bgrid, 256, 0, stream>>>(pairs_out, pairs_in, bucketCur,
                                                  binned, P, shift);
            resolve_kernel<<<(E + 1023) / 1024, 256, 0, stream>>>(binned, cursors,
                                                                  sorted, E);
        } else {
            dim3 sgrid((P + 1023) / 1024, KW);
            scatter_kernel<<<sgrid, 256, 0, stream>>>(pairs_out, pairs_in, cursors,
                                                      sorted, P);
        }

        // 512-thread blocks: 4 blocks/CU x 8 waves = 32 waves/CU.
        const int NRG = 512;
        int totW = NRG * 8;
        int rows0 = (N + 1) / 2;
        int rows1 = N - rows0;
        int rpw0 = (rows0 + totW - 1) / totW;
        int rpw1 = (rows1 + totW - 1) / totW;

        if (preconv) {
            cvt_kernel<<<(N * (CIN / 8) + 255) / 256, 256, 0, stream>>>(
                features, feat16, N * (CIN / 8));
            fused_wave_kernel<1><<<NRG * 2, 512, 0, stream>>>(
                features, feat16, weight, sorted, offsets, out, stats,
                N, E, 0, rows0, rpw0, KW);
            fused_wave_kernel<1><<<NRG * 2, 512, 0, stream>>>(
                features, feat16, weight, sorted, offsets, out, stats,
                N, E, rows0, rows1, rpw1, KW);
        } else {
            fused_wave_kernel<0><<<NRG * 2, 512, 0, stream>>>(
                features, feat16, weight, sorted, offsets, out, stats,
                N, E, 0, rows0, rpw0, KW);
            fused_wave_kernel<0><<<NRG * 2, 512, 0, stream>>>(
                features, feat16, weight, sorted, offsets, out, stats,
                N, E, rows0, rows1, rpw1, KW);
        }

        norm2_kernel<<<(n4 + 255) / 256, 256, 0, stream>>>(out, stats, gamma, beta,
                                                           n4, 1.0f / (float)N);
    } else {
        hipMemsetAsync(d_out, 0, (size_t)out_size * sizeof(float), stream);
        hipMemsetAsync(d_ws, 0, 64 * sizeof(float), stream);
        dim3 cgrid((P + 255) / 256, KW);
        conv_atomic_kernel<<<cgrid, 256, 0, stream>>>(features, weight, pairs_in,
                                                      pairs_out, (float*)d_out, P);
        stats_fb_kernel<<<512, 256, 0, stream>>>((const float*)d_out, (float*)d_ws, n4);
        norm_fb_kernel<<<(n4 + 255) / 256, 256, 0, stream>>>((float*)d_out, (float*)d_ws,
                                                             gamma, beta, n4,
                                                             1.0f / (float)N);
    }
}

// Round 13
// 1153.703 us; speedup vs baseline: 1.3150x; 1.3150x over previous
//
#include <hip/hip_runtime.h>
#include <hip/hip_fp16.h>

#define CIN 32
#define COUT 32
#define LRELU_SLOPE 0.01f
#define BN_EPS 1e-5f
#define CHUNK 2048
#define KMAX 27
#define NBUCK 256
#define BCH 4096
#define BROWS_MAX 2048

typedef _Float16 half2_t __attribute__((ext_vector_type(2)));

#if __has_builtin(__builtin_amdgcn_fdot2)
#define FDOT2(a, b, c) __builtin_amdgcn_fdot2((a), (b), (c), false)
#else
static __device__ __forceinline__ float fdot2_sw(half2_t a, half2_t b, float c) {
    return (float)a.x * (float)b.x + (float)a.y * (float)b.y + c;
}
#define FDOT2(a, b, c) fdot2_sw((a), (b), (c))
#endif

#if __has_builtin(__builtin_amdgcn_cvt_pkrtz)
#define CVTPK(x, y) __builtin_bit_cast(half2_t, __builtin_amdgcn_cvt_pkrtz((x), (y)))
#else
static __device__ __forceinline__ half2_t cvtpk_sw(float x, float y) {
    half2_t r; r.x = (_Float16)x; r.y = (_Float16)y; return r;
}
#define CVTPK(x, y) cvtpk_sw((x), (y))
#endif

union HU { uint4 u; half2_t h[4]; };
union FU { uint4 u; float f[4]; };

// ---------------- CSR build ----------------

__global__ void __launch_bounds__(256) hist_kernel(
    const int* __restrict__ po, int* __restrict__ cnt, int E)
{
    int i0 = (blockIdx.x * blockDim.x + threadIdx.x) * 4;
    if (i0 + 3 < E) {
        int4 v = *(const int4*)(po + i0);
        atomicAdd(&cnt[v.x], 1);
        atomicAdd(&cnt[v.y], 1);
        atomicAdd(&cnt[v.z], 1);
        atomicAdd(&cnt[v.w], 1);
    } else {
        for (int i = i0; i < E; ++i) atomicAdd(&cnt[po[i]], 1);
    }
}

__global__ void __launch_bounds__(256) blocksum_kernel(
    const int* __restrict__ cnt, int* __restrict__ bsum, int N)
{
    int base = blockIdx.x * CHUNK + threadIdx.x * 8;
    int s = 0;
#pragma unroll
    for (int j = 0; j < 8; ++j) { int i = base + j; if (i < N) s += cnt[i]; }
#pragma unroll
    for (int off = 1; off < 64; off <<= 1) s += __shfl_xor(s, off);
    __shared__ int wsum[4];
    if ((threadIdx.x & 63) == 0) wsum[threadIdx.x >> 6] = s;
    __syncthreads();
    if (threadIdx.x == 0) bsum[blockIdx.x] = wsum[0] + wsum[1] + wsum[2] + wsum[3];
}

// parallel exclusive scan of up to 1024 block sums, one block of 256 threads
__global__ void __launch_bounds__(256) scanblk_kernel(
    const int* __restrict__ bsum, int* __restrict__ boffs, int nb)
{
    __shared__ int ts[256];
    int tid = threadIdx.x;
    int v[4]; int s = 0;
#pragma unroll
    for (int j = 0; j < 4; ++j) {
        int i = tid * 4 + j;
        v[j] = (i < nb) ? bsum[i] : 0;
        s += v[j];
    }
    ts[tid] = s;
    __syncthreads();
    for (int off = 1; off < 256; off <<= 1) {
        int add = (tid >= off) ? ts[tid - off] : 0;
        __syncthreads();
        ts[tid] += add;
        __syncthreads();
    }
    int run = ts[tid] - s;
#pragma unroll
    for (int j = 0; j < 4; ++j) {
        int i = tid * 4 + j;
        if (i < nb) { boffs[i] = run; run += v[j]; }
    }
}

__global__ void __launch_bounds__(256) scatteroffs_kernel(
    int* __restrict__ cnt, int* __restrict__ cursors,
    const int* __restrict__ boffs, int N)
{
    int tid = threadIdx.x;
    int lane = tid & 63;
    int wv = tid >> 6;
    int base = blockIdx.x * CHUNK + tid * 8;
    int c[8]; int tsum = 0;
#pragma unroll
    for (int j = 0; j < 8; ++j) { int i = base + j; c[j] = (i < N) ? cnt[i] : 0; tsum += c[j]; }
    // wave inclusive scan of tsum
    int x = tsum;
#pragma unroll
    for (int off = 1; off < 64; off <<= 1) {
        int y = __shfl_up(x, off);
        if (lane >= off) x += y;
    }
    __shared__ int wtot[4];
    if (lane == 63) wtot[wv] = x;
    __syncthreads();
    int woff = boffs[blockIdx.x];
    for (int w = 0; w < wv; ++w) woff += wtot[w];
    int off = woff + x - tsum;
#pragma unroll
    for (int j = 0; j < 8; ++j) {
        int i = base + j;
        if (i < N) { cnt[i] = off; cursors[i] = off; off += c[j]; }
    }
}

// ---------------- two-phase scatter ----------------
// R11: one-phase scatter WRITE_SIZE=425MB for a 27MB output (64B-line write
// amplification). R12: resolve with ~54 blocks/bucket spread over 8 XCDs kept
// WRITE_SIZE at 423MB -- per-XCD L2s are CU-side and non-coherent, so a line
// dirtied from multiple XCDs is written back multiple times. FIX: one
// workgroup owns one WHOLE bucket (2048 rows, ~55K entries, 110KB CSR
// window) -> every write to a line comes from ONE XCD's L2; cursors live in
// LDS so slot atomics never touch L2 at all.

__global__ void __launch_bounds__(256) bucketinit_kernel(
    const int* __restrict__ offsets, int* __restrict__ bucketCur,
    int N, int E, int shift)
{
    int b = threadIdx.x;
    long idx = (long)b << shift;
    bucketCur[b] = (idx < N) ? offsets[idx] : E;
}

__global__ void __launch_bounds__(256) bin_kernel(
    const int* __restrict__ pairs_out, const int* __restrict__ pairs_in,
    int* __restrict__ bucketCur, uint2* __restrict__ binned,
    int P, int shift)
{
    __shared__ uint2 buf[BCH];          // 32 KB
    __shared__ int hist[NBUCK];
    __shared__ int ts[NBUCK];
    __shared__ int lbase[NBUCK];
    __shared__ int gbase[NBUCK];
    __shared__ int lcur[NBUCK];
    int tid = threadIdx.x;
    int k = blockIdx.y;
    int p0 = blockIdx.x * BCH;
    const int* po = pairs_out + (size_t)k * P;
    const int* pi = pairs_in  + (size_t)k * P;

    hist[tid] = 0;
    __syncthreads();

    int myP[16], myV[16];
#pragma unroll
    for (int j = 0; j < 4; ++j) {
        int idx = p0 + j * 1024 + tid * 4;
        if (idx + 3 < P) {
            int4 o4 = *(const int4*)(po + idx);
            int4 i4 = *(const int4*)(pi + idx);
            myP[j*4+0] = o4.x; myV[j*4+0] = (i4.x << 6) | k;
            myP[j*4+1] = o4.y; myV[j*4+1] = (i4.y << 6) | k;
            myP[j*4+2] = o4.z; myV[j*4+2] = (i4.z << 6) | k;
            myP[j*4+3] = o4.w; myV[j*4+3] = (i4.w << 6) | k;
        } else {
#pragma unroll
            for (int q = 0; q < 4; ++q) {
                int ii = idx + q;
                if (ii < P) { myP[j*4+q] = po[ii]; myV[j*4+q] = (pi[ii] << 6) | k; }
                else myP[j*4+q] = -1;
            }
        }
    }
#pragma unroll
    for (int x = 0; x < 16; ++x)
        if (myP[x] >= 0) atomicAdd(&hist[myP[x] >> shift], 1);
    __syncthreads();

    int h = hist[tid];
    ts[tid] = h;
    __syncthreads();
    for (int off = 1; off < NBUCK; off <<= 1) {
        int add = (tid >= off) ? ts[tid - off] : 0;
        __syncthreads();
        ts[tid] += add;
        __syncthreads();
    }
    lbase[tid] = ts[tid] - h;
    lcur[tid]  = ts[tid] - h;
    if (h > 0) gbase[tid] = atomicAdd(&bucketCur[tid], h);
    __syncthreads();

#pragma unroll
    for (int x = 0; x < 16; ++x) {
        if (myP[x] >= 0) {
            int b = myP[x] >> shift;
            int pos = atomicAdd(&lcur[b], 1);
            buf[pos] = make_uint2((unsigned)myP[x], (unsigned)myV[x]);
        }
    }
    __syncthreads();
    {
        int n = hist[tid];
        if (n > 0) {
            int src = lbase[tid], dst = gbase[tid];
            for (int i = 0; i < n; ++i) binned[dst + i] = buf[src + i];
        }
    }
}

// one block per bucket; LDS cursors; all writes to a line from one XCD
__global__ void __launch_bounds__(1024) resolve_bucket_kernel(
    const uint2* __restrict__ binned, const int* __restrict__ offsets,
    int* __restrict__ sorted, int N, int E, int shift)
{
    __shared__ int lcur[BROWS_MAX];
    int tid = threadIdx.x;
    int rowLo = blockIdx.x << shift;
    int rows = 1 << shift;
    if (rowLo + rows > N) rows = N - rowLo;
    for (int i = tid; i < rows; i += 1024) lcur[i] = offsets[rowLo + i];
    __syncthreads();
    int begE = offsets[rowLo];
    int endE = (rowLo + rows >= N) ? E : offsets[rowLo + rows];
    for (int i = begE + tid; i < endE; i += 1024) {
        uint2 e = binned[i];
        int slot = atomicAdd(&lcur[(int)e.x - rowLo], 1);
        sorted[slot] = (int)e.y;
    }
}

// fallback one-phase scatter (ws too small for binned[], or bucket > 2048 rows)
__global__ void __launch_bounds__(256) scatter_kernel(
    const int* __restrict__ pairs_out, const int* __restrict__ pairs_in,
    int* __restrict__ cursors, int* __restrict__ sorted, int P)
{
    int p0 = (blockIdx.x * blockDim.x + threadIdx.x) * 4;
    int k = blockIdx.y;
    const int* po = pairs_out + (size_t)k * P;
    const int* pi = pairs_in + (size_t)k * P;
    if (p0 + 3 < P) {
        int4 o4 = *(const int4*)(po + p0);
        int4 i4 = *(const int4*)(pi + p0);
        int s0 = atomicAdd(&cursors[o4.x], 1); sorted[s0] = (i4.x << 6) | k;
        int s1 = atomicAdd(&cursors[o4.y], 1); sorted[s1] = (i4.y << 6) | k;
        int s2 = atomicAdd(&cursors[o4.z], 1); sorted[s2] = (i4.z << 6) | k;
        int s3 = atomicAdd(&cursors[o4.w], 1); sorted[s3] = (i4.w << 6) | k;
    } else {
        for (int p = p0; p < P; ++p) {
            int slot = atomicAdd(&cursors[po[p]], 1);
            sorted[slot] = (pi[p] << 6) | k;
        }
    }
}

// ---------------- features -> f16 pre-convert ----------------

__global__ void __launch_bounds__(256) cvt_kernel(
    const float* __restrict__ f, __half* __restrict__ o, int n8)
{
    int i = blockIdx.x * 256 + threadIdx.x;
    if (i >= n8) return;
    const float4* s = (const float4*)f + (size_t)i * 2;
    float4 a = s[0], b = s[1];
    union { uint4 u; __half h[8]; } r;
    r.h[0] = __float2half(a.x); r.h[1] = __float2half(a.y);
    r.h[2] = __float2half(a.z); r.h[3] = __float2half(a.w);
    r.h[4] = __float2half(b.x); r.h[5] = __float2half(b.y);
    r.h[6] = __float2half(b.z); r.h[7] = __float2half(b.w);
    ((uint4*)o)[i] = r.u;
}

// ---------------- fused conv + lrelu + stats ----------------
// 512-thread blocks (8 waves share one 28KB W-copy): 4 blocks/CU = 32 waves/CU.
// Two half-N dispatches (observability). co-half from blockIdx bit 3 (same-XCD
// sibling: halved FETCH, R8). Entry word via readlane -> SALU decode. W_k LDS
// slice 1KB contiguous, conflict-free. Stats dup j-lanes: last-writer-wins.

template<int PC>
__global__ void __launch_bounds__(512, 8) fused_wave_kernel(
    const float* __restrict__ features,
    const __half* __restrict__ feat16,
    const float* __restrict__ weight,
    const int* __restrict__ sorted,
    const int* __restrict__ offsets,
    float* __restrict__ out,
    float* __restrict__ gstats,         // [0..31] sum, [32..63] sumsq
    int N, int E, int rowBase, int rowCount, int rpw, int KW)
{
    __shared__ __align__(16) __half wlds[KMAX * 512];   // [k][co_local(16)][c(32)] = 27,648 B
    __shared__ float sred[8][16];
    __shared__ float qred[8][16];

    const int co_base = ((blockIdx.x >> 3) & 1) << 4;
    const int rg = (blockIdx.x & 7) | ((blockIdx.x >> 4) << 3);

    // stage W slice: global fp32 [k][c][co] -> LDS f16 [k][co_local][c]
    for (int s = threadIdx.x; s < KW * 512; s += 512) {
        int co_l = s & 15, c = (s >> 4) & 31, k = s >> 9;
        wlds[k * 512 + co_l * 32 + c] =
            __float2half(weight[k * 1024 + c * 32 + co_base + co_l]);
    }
    __syncthreads();

    const int lane = threadIdx.x & 63;
    const int wv = threadIdx.x >> 6;   // 0..7
    const int j = lane & 3;            // c-quarter
    const int co_l = lane >> 2;        // 0..15
    const int gw = rg * 8 + wv;
    const int wlane_off = lane << 4;
    const char* wbase = (const char*)wlds;
    const char* fbase = PC ? (const char*)feat16 : (const char*)features;

    float ssum = 0.f, qsum = 0.f;

    int i0 = rowBase + gw * rpw;
    int i1 = i0 + rpw;
    int rend = rowBase + rowCount; if (rend > N) rend = N;
    if (i1 > rend) i1 = rend;

#define LOADE(F0, F1, W0, IDX) do {                                               \
    int _ii = (IDX); _ii = _ii < 63 ? _ii : 63;                                   \
    int _pk = __builtin_amdgcn_readlane(pkl, _ii);                                \
    W0 = *(const uint4*)(wbase + ((_pk & 63) << 10) + wlane_off);                 \
    if (PC) {                                                                     \
        const char* _sb = fbase + (unsigned)(_pk & 0xFFFFFFC0);                   \
        F0 = *(const uint4*)(_sb + (j << 4));                                     \
    } else {                                                                      \
        const char* _sb = fbase + ((size_t)(unsigned)(_pk & 0xFFFFFFC0) << 1);    \
        F0 = *(const uint4*)(_sb + (j << 5));                                     \
        F1 = *(const uint4*)(_sb + (j << 5) + 16);                                \
    }                                                                             \
} while (0)

#define DOTS(F0, F1, W0) do {                                                     \
    HU _w; _w.u = W0;                                                             \
    half2_t _p0, _p1, _p2, _p3;                                                   \
    if (PC) {                                                                     \
        HU _f; _f.u = F0;                                                         \
        _p0 = _f.h[0]; _p1 = _f.h[1]; _p2 = _f.h[2]; _p3 = _f.h[3];               \
    } else {                                                                      \
        FU _a, _b; _a.u = F0; _b.u = F1;                                          \
        _p0 = CVTPK(_a.f[0], _a.f[1]); _p1 = CVTPK(_a.f[2], _a.f[3]);             \
        _p2 = CVTPK(_b.f[0], _b.f[1]); _p3 = CVTPK(_b.f[2], _b.f[3]);             \
    }                                                                             \
    acc0 = FDOT2(_p0, _w.h[0], acc0); acc1 = FDOT2(_p1, _w.h[1], acc1);           \
    acc0 = FDOT2(_p2, _w.h[2], acc0); acc1 = FDOT2(_p3, _w.h[3], acc1);           \
} while (0)

#define WINDOW() do {                                                             \
    uint4 fA0, fA1, wA0, fB0, fB1, wB0, fC0, fC1, wC0, fD0, fD1, wD0;             \
    LOADE(fA0, fA1, wA0, 0);                                                      \
    LOADE(fB0, fB1, wB0, 1);                                                      \
    LOADE(fC0, fC1, wC0, 2);                                                      \
    LOADE(fD0, fD1, wD0, 3);                                                      \
    for (int e = 0; e < m; e += 4) {                                              \
        DOTS(fA0, fA1, wA0); LOADE(fA0, fA1, wA0, e + 4);                         \
        if (e + 1 < m) { DOTS(fB0, fB1, wB0); LOADE(fB0, fB1, wB0, e + 5); }      \
        if (e + 2 < m) { DOTS(fC0, fC1, wC0); LOADE(fC0, fC1, wC0, e + 6); }      \
        if (e + 3 < m) { DOTS(fD0, fD1, wD0); LOADE(fD0, fD1, wD0, e + 7); }      \
    }                                                                             \
} while (0)

    if (i0 < rend) {
        int beg = offsets[i0];
        int pklA;
        {
            int end0 = (i0 == N - 1) ? E : offsets[i0 + 1];
            int m0 = end0 - beg; if (m0 > 64) m0 = 64;
            pklA = (lane < m0) ? sorted[beg + lane] : 0;
        }
        for (int r = i0; r < i1; ++r) {
            int end = (r == N - 1) ? E : offsets[r + 1];
            int pklB = 0;
            if (r + 1 < i1) {
                int endn = (r + 1 == N - 1) ? E : offsets[r + 2];
                int mn = endn - end; if (mn > 64) mn = 64;
                pklB = (lane < mn) ? sorted[end + lane] : 0;
            }
            float acc0 = 0.f, acc1 = 0.f;
            if (end > beg) {
                {
                    int m = end - beg; if (m > 64) m = 64;
                    int pkl = pklA;
                    WINDOW();
                }
                for (int base = beg + 64; base < end; base += 64) {   // rare
                    int m = end - base; if (m > 64) m = 64;
                    int pkl = (lane < m) ? sorted[base + lane] : 0;
                    WINDOW();
                }
            }
            float acc = acc0 + acc1;
            acc += __shfl_xor(acc, 1);     // combine c-quarters
            acc += __shfl_xor(acc, 2);
            float act = acc >= 0.f ? acc : LRELU_SLOPE * acc;
            if (j == 0) out[(size_t)r * COUT + co_base + co_l] = act;
            ssum += act; qsum += act * act;
            beg = end; pklA = pklB;
        }
    }

#undef WINDOW
#undef LOADE
#undef DOTS

    sred[wv][co_l] = ssum;   // 4 j-lanes write identical value; one survives (correct)
    qred[wv][co_l] = qsum;
    __syncthreads();
    if (threadIdx.x < 16) {
        int t = threadIdx.x;
        float S = 0.f, Q = 0.f;
#pragma unroll
        for (int w = 0; w < 8; ++w) { S += sred[w][t]; Q += qred[w][t]; }
        atomicAdd(&gstats[co_base + t], S);
        atomicAdd(&gstats[32 + co_base + t], Q);
    }
}

// norm WITHOUT re-applying lrelu
__global__ void __launch_bounds__(256) norm2_kernel(
    float* __restrict__ data, const float* __restrict__ stats,
    const float* __restrict__ gamma, const float* __restrict__ beta,
    int n4, float invN)
{
    int i = blockIdx.x * blockDim.x + threadIdx.x;
    if (i >= n4) return;
    int qd = i & 7;
    float sc[4], bs[4];
#pragma unroll
    for (int j = 0; j < 4; ++j) {
        int c = qd * 4 + j;
        float m = stats[c] * invN;
        float v = stats[32 + c] * invN - m * m;
        float inv = rsqrtf(v + BN_EPS);
        sc[j] = inv * gamma[c];
        bs[j] = beta[c] - m * sc[j];
    }
    float4* d4 = (float4*)data;
    float4 a = d4[i];
    float4 y;
    y.x = a.x * sc[0] + bs[0];
    y.y = a.y * sc[1] + bs[1];
    y.z = a.z * sc[2] + bs[2];
    y.w = a.w * sc[3] + bs[3];
    d4[i] = y;
}

// ---------------- fallback path (atomic version) ----------------

__global__ void __launch_bounds__(256) conv_atomic_kernel(
    const float* __restrict__ features,
    const float* __restrict__ weight,
    const int* __restrict__ pairs_in,
    const int* __restrict__ pairs_out,
    float* __restrict__ out,
    int P)
{
    int p = blockIdx.x * blockDim.x + threadIdx.x;
    int k = blockIdx.y;
    if (p >= P) return;
    int pi = pairs_in[(size_t)k * P + p];
    int po = pairs_out[(size_t)k * P + p];
    const float4* __restrict__ frow = (const float4*)(features + (size_t)pi * CIN);
    const float* __restrict__ wk = weight + (size_t)k * CIN * COUT;
    float acc[COUT];
#pragma unroll
    for (int co = 0; co < COUT; ++co) acc[co] = 0.f;
#pragma unroll
    for (int c4 = 0; c4 < CIN / 4; ++c4) {
        float4 f = frow[c4];
        float fv[4] = {f.x, f.y, f.z, f.w};
#pragma unroll
        for (int j = 0; j < 4; ++j) {
            const float* __restrict__ wr = wk + (c4 * 4 + j) * COUT;
#pragma unroll
            for (int co = 0; co < COUT; ++co)
                acc[co] = fmaf(fv[j], wr[co], acc[co]);
        }
    }
    float* orow = out + (size_t)po * COUT;
#pragma unroll
    for (int co = 0; co < COUT; ++co)
        atomicAdd(orow + co, acc[co]);
}

__device__ __forceinline__ float4 lrelu4(float4 v) {
    float4 a;
    a.x = v.x >= 0.f ? v.x : LRELU_SLOPE * v.x;
    a.y = v.y >= 0.f ? v.y : LRELU_SLOPE * v.y;
    a.z = v.z >= 0.f ? v.z : LRELU_SLOPE * v.z;
    a.w = v.w >= 0.f ? v.w : LRELU_SLOPE * v.w;
    return a;
}

__global__ void __launch_bounds__(256) stats_fb_kernel(
    const float* __restrict__ conv, float* __restrict__ stats, int n4)
{
    const float4* __restrict__ c4p = (const float4*)conv;
    int stride = blockDim.x * gridDim.x;
    float4 s = {0.f, 0.f, 0.f, 0.f};
    float4 q = {0.f, 0.f, 0.f, 0.f};
    for (int i = blockIdx.x * blockDim.x + threadIdx.x; i < n4; i += stride) {
        float4 a = lrelu4(c4p[i]);
        s.x += a.x; s.y += a.y; s.z += a.z; s.w += a.w;
        q.x += a.x * a.x; q.y += a.y * a.y; q.z += a.z * a.z; q.w += a.w * a.w;
    }
#pragma unroll
    for (int off = 8; off < 64; off <<= 1) {
        s.x += __shfl_xor(s.x, off); s.y += __shfl_xor(s.y, off);
        s.z += __shfl_xor(s.z, off); s.w += __shfl_xor(s.w, off);
        q.x += __shfl_xor(q.x, off); q.y += __shfl_xor(q.y, off);
        q.z += __shfl_xor(q.z, off); q.w += __shfl_xor(q.w, off);
    }
    __shared__ float4 rs[4][8];
    __shared__ float4 rq[4][8];
    int lane = threadIdx.x & 63;
    int w = threadIdx.x >> 6;
    if (lane < 8) { rs[w][lane] = s; rq[w][lane] = q; }
    __syncthreads();
    if (threadIdx.x < 8) {
        int qd = threadIdx.x;
        float4 S = {0.f, 0.f, 0.f, 0.f};
        float4 Q = {0.f, 0.f, 0.f, 0.f};
        for (int ww = 0; ww < 4; ++ww) {
            float4 a = rs[ww][qd], b = rq[ww][qd];
            S.x += a.x; S.y += a.y; S.z += a.z; S.w += a.w;
            Q.x += b.x; Q.y += b.y; Q.z += b.z; Q.w += b.w;
        }
        atomicAdd(&stats[qd * 4 + 0], S.x); atomicAdd(&stats[qd * 4 + 1], S.y);
        atomicAdd(&stats[qd * 4 + 2], S.z); atomicAdd(&stats[qd * 4 + 3], S.w);
        atomicAdd(&stats[32 + qd * 4 + 0], Q.x); atomicAdd(&stats[32 + qd * 4 + 1], Q.y);
        atomicAdd(&stats[32 + qd * 4 + 2], Q.z); atomicAdd(&stats[32 + qd * 4 + 3], Q.w);
    }
}

__global__ void __launch_bounds__(256) norm_fb_kernel(
    float* __restrict__ data, const float* __restrict__ stats,
    const float* __restrict__ gamma, const float* __restrict__ beta,
    int n4, float invN)
{
    int i = blockIdx.x * blockDim.x + threadIdx.x;
    if (i >= n4) return;
    int qd = i & 7;
    float sc[4], bs[4];
#pragma unroll
    for (int j = 0; j < 4; ++j) {
        int c = qd * 4 + j;
        float m = stats[c] * invN;
        float v = stats[32 + c] * invN - m * m;
        float inv = rsqrtf(v + BN_EPS);
        sc[j] = inv * gamma[c];
        bs[j] = beta[c] - m * sc[j];
    }
    float4* d4 = (float4*)data;
    float4 a = lrelu4(d4[i]);
    float4 y;
    y.x = a.x * sc[0] + bs[0];
    y.y = a.y * sc[1] + bs[1];
    y.z = a.z * sc[2] + bs[2];
    y.w = a.w * sc[3] + bs[3];
    d4[i] = y;
}

extern "C" void kernel_launch(void* const* d_in, const int* in_sizes, int n_in,
                              void* d_out, int out_size, void* d_ws, size_t ws_size,
                              hipStream_t stream) {
    const float* features = (const float*)d_in[0];
    const float* weight   = (const float*)d_in[1];
    const float* gamma    = (const float*)d_in[2];
    const float* beta     = (const float*)d_in[3];
    const int* pairs_in   = (const int*)d_in[4];
    const int* pairs_out  = (const int*)d_in[5];
    float* out = (float*)d_out;

    int N  = in_sizes[0] / CIN;           // 500000
    int KW = in_sizes[1] / (CIN * COUT);  // 27
    int P  = in_sizes[4] / KW;            // 250000
    int E  = KW * P;                      // 6,750,000
    int n4 = N * (COUT / 4);

    // ws layout: stats(256B) | offsets[N] | cursors[N] | bsum[1024] | boffs[1024]
    //            | sorted[E] | pad | feat16[N*32] | pad | bucketCur[256] | binned[E]x8B
    char* wsb = (char*)d_ws;
    float* stats  = (float*)wsb;
    int* offsets  = (int*)(wsb + 256);
    int* cursors  = offsets + N;
    int* bsum     = cursors + N;
    int* boffs    = bsum + 1024;
    int* sorted   = boffs + 1024;
    __half* feat16 = (__half*)(((uintptr_t)(sorted + E) + 15) & ~(uintptr_t)15);
    int* bucketCur = (int*)(((uintptr_t)(feat16 + (size_t)N * CIN) + 15) & ~(uintptr_t)15);
    uint2* binned  = (uint2*)(bucketCur + NBUCK);   // 1024B after bucketCur, 16B-aligned

    size_t need1 = 256 + ((size_t)2 * N + 2048 + E) * 4;
    size_t need2 = need1 + 16 + (size_t)N * CIN * 2;
    size_t need3 = need2 + 16 + NBUCK * 4 + (size_t)E * 8;

    // bucket shift: smallest so that all rows fit in NBUCK buckets
    int shift = 0;
    while (((N - 1) >> shift) >= NBUCK) shift++;

    bool fast = (ws_size >= need1) && (KW <= KMAX) && (N <= (1 << 24));
    bool preconv = fast && (ws_size >= need2);
    bool twophase = preconv && (ws_size >= need3) && ((1 << shift) <= BROWS_MAX);

    if (fast) {
        hipMemsetAsync(stats, 0, 256, stream);
        hipMemsetAsync(offsets, 0, (size_t)N * sizeof(int), stream);

        hist_kernel<<<(E / 4 + 255) / 256, 256, 0, stream>>>(pairs_out, offsets, E);

        int nb = (N + CHUNK - 1) / CHUNK;
        blocksum_kernel<<<nb, 256, 0, stream>>>(offsets, bsum, N);
        scanblk_kernel<<<1, 256, 0, stream>>>(bsum, boffs, nb);
        scatteroffs_kernel<<<nb, 256, 0, stream>>>(offsets, cursors, boffs, N);

        if (twophase) {
            bucketinit_kernel<<<1, NBUCK, 0, stream>>>(offsets, bucketCur, N, E, shift);
            dim3 bgrid((P + BCH - 1) / BCH, KW);
            bin_kernel<<<bgrid, 256, 0, stream>>>(pairs_out, pairs_in, bucketCur,
                                                  binned, P, shift);
            int nbuckets = (N + (1 << shift) - 1) >> shift;
            resolve_bucket_kernel<<<nbuckets, 1024, 0, stream>>>(
                binned, offsets, sorted, N, E, shift);
        } else {
            dim3 sgrid((P + 1023) / 1024, KW);
            scatter_kernel<<<sgrid, 256, 0, stream>>>(pairs_out, pairs_in, cursors,
                                                      sorted, P);
        }

        // 512-thread blocks: 4 blocks/CU x 8 waves = 32 waves/CU.
        const int NRG = 512;
        int totW = NRG * 8;
        int rows0 = (N + 1) / 2;
        int rows1 = N - rows0;
        int rpw0 = (rows0 + totW - 1) / totW;
        int rpw1 = (rows1 + totW - 1) / totW;

        if (preconv) {
            cvt_kernel<<<(N * (CIN / 8) + 255) / 256, 256, 0, stream>>>(
                features, feat16, N * (CIN / 8));
            fused_wave_kernel<1><<<NRG * 2, 512, 0, stream>>>(
                features, feat16, weight, sorted, offsets, out, stats,
                N, E, 0, rows0, rpw0, KW);
            fused_wave_kernel<1><<<NRG * 2, 512, 0, stream>>>(
                features, feat16, weight, sorted, offsets, out, stats,
                N, E, rows0, rows1, rpw1, KW);
        } else {
            fused_wave_kernel<0><<<NRG * 2, 512, 0, stream>>>(
                features, feat16, weight, sorted, offsets, out, stats,
                N, E, 0, rows0, rpw0, KW);
            fused_wave_kernel<0><<<NRG * 2, 512, 0, stream>>>(
                features, feat16, weight, sorted, offsets, out, stats,
                N, E, rows0, rows1, rpw1, KW);
        }

        norm2_kernel<<<(n4 + 255) / 256, 256, 0, stream>>>(out, stats, gamma, beta,
                                                           n4, 1.0f / (float)N);
    } else {
        hipMemsetAsync(d_out, 0, (size_t)out_size * sizeof(float), stream);
        hipMemsetAsync(d_ws, 0, 64 * sizeof(float), stream);
        dim3 cgrid((P + 255) / 256, KW);
        conv_atomic_kernel<<<cgrid, 256, 0, stream>>>(features, weight, pairs_in,
                                                      pairs_out, (float*)d_out, P);
        stats_fb_kernel<<<512, 256, 0, stream>>>((const float*)d_out, (float*)d_ws, n4);
        norm_fb_kernel<<<(n4 + 255) / 256, 256, 0, stream>>>((float*)d_out, (float*)d_ws,
                                                             gamma, beta, n4,
                                                             1.0f / (float)N);
    }
}